// Round 1
// baseline (755.442 us; speedup 1.0000x reference)
//
#include <hip/hip_runtime.h>

typedef __bf16 bf16x8 __attribute__((ext_vector_type(8)));
typedef float f32x4 __attribute__((ext_vector_type(4)));

constexpr int CH = 128;
constexpr int FD = 1024;

__device__ inline bf16x8 cvt_bf16x8(f32x4 lo, f32x4 hi) {
    bf16x8 r;
    r[0] = (__bf16)lo[0]; r[1] = (__bf16)lo[1];
    r[2] = (__bf16)lo[2]; r[3] = (__bf16)lo[3];
    r[4] = (__bf16)hi[0]; r[5] = (__bf16)hi[1];
    r[6] = (__bf16)hi[2]; r[7] = (__bf16)hi[3];
    return r;
}

// One block = 1 channel c, g-tile of 256. 4 waves, each wave does a 64x64 tile.
// A (x) and B (W) fragments loaded straight from global (both K-contiguous),
// converted fp32->bf16 in-register. Memory-bound: goal is streaming W at HBM BW.
__global__ __launch_bounds__(256, 2)
void cw_linear_kernel(const float* __restrict__ x, const float* __restrict__ W,
                      const float* __restrict__ bias, float* __restrict__ y)
{
    const int c    = blockIdx.x & (CH - 1);   // 128 | 8 XCDs: all 4 tiles of a
    const int tile = blockIdx.x >> 7;         // channel land on one XCD -> x_c hot in L2
    const int wave = threadIdx.x >> 6;
    const int lane = threadIdx.x & 63;
    const int l16  = lane & 15;               // m (A) / n (B) index within 16
    const int kq   = lane >> 4;               // k-chunk of 8 (0..3)

    const int g0 = tile * 256 + wave * 64;    // wave's g range [g0, g0+64)

    // x[m, c, k]: offset (m*CH + c)*FD + k   ; lane reads m = l16 + 16*mt
    // W[c, g, k]: offset (c*FD + g)*FD + k   ; lane reads g = g0 + l16 + 16*nt
    const float* xp = x + ((size_t)l16 * CH + c) * FD + kq * 8;
    const float* wp = W + ((size_t)c * FD + g0 + l16) * FD + kq * 8;

    f32x4 acc[4][4] = {};   // acc[mt][nt]

    for (int k0 = 0; k0 < FD; k0 += 32) {
        bf16x8 a[4], b[4];
#pragma unroll
        for (int mt = 0; mt < 4; ++mt) {
            const float* p = xp + (size_t)mt * 16 * CH * FD + k0;
            f32x4 lo = *(const f32x4*)p;
            f32x4 hi = *(const f32x4*)(p + 4);
            a[mt] = cvt_bf16x8(lo, hi);
        }
#pragma unroll
        for (int nt = 0; nt < 4; ++nt) {
            const float* p = wp + (size_t)nt * 16 * FD + k0;
            f32x4 lo = __builtin_nontemporal_load((const f32x4*)p);      // W: zero reuse,
            f32x4 hi = __builtin_nontemporal_load((const f32x4*)p + 1);  // don't pollute L2
            b[nt] = cvt_bf16x8(lo, hi);
        }
#pragma unroll
        for (int mt = 0; mt < 4; ++mt)
#pragma unroll
            for (int nt = 0; nt < 4; ++nt)
                acc[mt][nt] = __builtin_amdgcn_mfma_f32_16x16x32_bf16(
                    a[mt], b[nt], acc[mt][nt], 0, 0, 0);
    }

    // Epilogue. C/D layout: col(n) = lane&15, row(m within 16) = (lane>>4)*4 + r.
#pragma unroll
    for (int nt = 0; nt < 4; ++nt) {
        const int g = g0 + nt * 16 + l16;
        const float bv = bias[c * FD + g];
#pragma unroll
        for (int mt = 0; mt < 4; ++mt) {
#pragma unroll
            for (int r = 0; r < 4; ++r) {
                const int m = mt * 16 + kq * 4 + r;
                y[((size_t)m * CH + c) * FD + g] = acc[mt][nt][r] + bv;
            }
        }
    }
}

extern "C" void kernel_launch(void* const* d_in, const int* in_sizes, int n_in,
                              void* d_out, int out_size, void* d_ws, size_t ws_size,
                              hipStream_t stream) {
    const float* x = (const float*)d_in[0];
    const float* W = (const float*)d_in[1];
    const float* b = (const float*)d_in[2];
    float* y = (float*)d_out;

    dim3 grid(512);   // 128 channels * 4 g-tiles
    dim3 block(256);  // 4 waves
    cw_linear_kernel<<<grid, block, 0, stream>>>(x, W, b, y);
}